// Round 10
// baseline (29.833 us; speedup 1.0000x reference)
//
#include <hip/hip_runtime.h>

#define C_IN  32
#define O_OUT 48
#define H_IN  96
#define W_IN  96
#define H_OUT 192
#define W_OUT 192
#define HW_IN (H_IN * W_IN)
#define NCBLK 384               // compute blocks: 2 b x 96 rows x 2 half
#define NFBLK 768               // frame blocks: 96 (b,o) x 8 segs

typedef __attribute__((ext_vector_type(8))) short bf16x8;
typedef __attribute__((ext_vector_type(4))) float f32x4;

__device__ __forceinline__ unsigned short f2bf(float f) {
    union { float f; unsigned u; } v; v.f = f;
    unsigned u = v.u + 0x7FFFu + ((v.u >> 16) & 1u);
    return (unsigned short)(u >> 16);
}

// ---------------------------------------------------------------------------
// Single kernel, two block roles.
// Compute blocks [0,384): (b,row,half). Phase A transposes the 3x50x32 x-slab
// to LDS (bf16). Each of the 6 waves (pe,mt) builds its 8 MFMA A-fragments
// from RAW weights in registers, folding the parity-class reciprocal norm and
// the row-edge class (ho=0 / ho=191: missing row-tap zeroed, norm over the
// present row only). MFMA then yields exact values for ALL rows; only the
// column borders wo in {0,191} are excluded by the store predicates.
// Frame blocks [384,1152): exact f32 for the two border columns + 4 corners.
//
// Tap map (ts = a*2+d), pe=0 (even ho=2s): a0->i=1 (x row s), a1->i=3 (s-1)
//                       pe=1 (odd  ho)   : a0->i=0 (s+1),     a1->i=2 (s)
// po=0 (even wo=2t): d0->j=1 (col t), d1->j=3 (t-1)
// po=1 (odd  wo)   : d0->j=0 (t+1),  d1->j=2 (t)
// w-row float4 (x,y,z,w) = (j0,j1,j2,j3); po=0 norm = .y+.w, po=1 = .x+.z
// ---------------------------------------------------------------------------
__global__ __launch_bounds__(384) void nct_all(
    const float* __restrict__ x,       // [2,32,96,96]
    const float* __restrict__ weight,  // [48,32,4,4]
    const float* __restrict__ bias,    // [48]
    float* __restrict__ out)           // [2,48,192,192]
{
    __shared__ __align__(16) unsigned short xs[3][52][32];
    const int blk = blockIdx.x;
    const int tid = threadIdx.x;

    if (blk < NCBLK) {
        int Wd = blk;
        const int half = Wd & 1; Wd >>= 1;
        const int row  = Wd % 96;
        const int b    = Wd / 96;
        const int c0   = half * 48;

        const int r3[3] = { (row > 0) ? row - 1 : 0, row, (row < H_IN - 1) ? row + 1 : H_IN - 1 };

        // ---- phase A: transpose 3 rows x 50 cols x 32 c into LDS ----
        for (int tau = tid; tau < 600; tau += 384) {
            const int r   = tau / 200;
            const int rem = tau - r * 200;
            const int pix = rem >> 2;
            const int cg  = rem & 3;
            int gcol = c0 - 1 + pix;
            gcol = (gcol < 0) ? 0 : ((gcol > W_IN - 1) ? W_IN - 1 : gcol);
            const float* src = x + (size_t)(b * C_IN + cg * 8) * HW_IN + r3[r] * W_IN + gcol;
            unsigned pk[4];
            #pragma unroll
            for (int k = 0; k < 4; ++k) {
                const float f0 = src[(size_t)(2 * k)     * HW_IN];
                const float f1 = src[(size_t)(2 * k + 1) * HW_IN];
                pk[k] = (unsigned)f2bf(f0) | ((unsigned)f2bf(f1) << 16);
            }
            *(uint4*)(&xs[r][pix][cg * 8]) = make_uint4(pk[0], pk[1], pk[2], pk[3]);
        }

        // ---- per-wave A-fragment build from raw weights ----
        const int lane = tid & 63;
        const int wid  = tid >> 6;     // 0..5
        const int pe = wid & 1, mt = wid >> 1;
        const int g = lane >> 4, n16 = lane & 15;

        const bool etop = (pe == 0 && row == 0);
        const bool ebot = (pe == 1 && row == H_IN - 1);
        const float m0 = ebot ? 0.f : 1.f;   // a0 tap present?
        const float m1 = etop ? 0.f : 1.f;   // a1 tap present?

        const int o = mt * 16 + n16;
        const float* wsrc = weight + ((size_t)o * C_IN + g * 8) * 16;

        bf16x8 A[2][4];
        #pragma unroll
        for (int cc = 0; cc < 8; ++cc) {
            const float4 w0 = *(const float4*)(wsrc + cc * 16);
            const float4 w1 = *(const float4*)(wsrc + cc * 16 + 4);
            const float4 w2 = *(const float4*)(wsrc + cc * 16 + 8);
            const float4 w3 = *(const float4*)(wsrc + cc * 16 + 12);
            const float4 wa0 = pe ? w0 : w1;   // a0 row taps
            const float4 wa1 = pe ? w2 : w3;   // a1 row taps

            const float r0 = 1.f / (m0 * (wa0.y + wa0.w) + m1 * (wa1.y + wa1.w)); // po=0
            const float r1 = 1.f / (m0 * (wa0.x + wa0.z) + m1 * (wa1.x + wa1.z)); // po=1

            A[0][0][cc] = (short)f2bf(m0 * wa0.y * r0);
            A[0][1][cc] = (short)f2bf(m0 * wa0.w * r0);
            A[0][2][cc] = (short)f2bf(m1 * wa1.y * r0);
            A[0][3][cc] = (short)f2bf(m1 * wa1.w * r0);
            A[1][0][cc] = (short)f2bf(m0 * wa0.x * r1);
            A[1][1][cc] = (short)f2bf(m0 * wa0.z * r1);
            A[1][2][cc] = (short)f2bf(m1 * wa1.x * r1);
            A[1][3][cc] = (short)f2bf(m1 * wa1.z * r1);
        }

        const float4 bv4 = *(const float4*)(bias + mt * 16 + 4 * g);

        __syncthreads();

        const int lr0 = pe ? 2 : 1;
        const int lr1 = pe ? 1 : 0;
        const int ho  = 2 * row + pe;

        #pragma unroll
        for (int nt = 0; nt < 3; ++nt) {
            const int lp = nt * 16 + n16 + 1;

            const bf16x8 B00 = *(const bf16x8*)(&xs[lr0][lp][g * 8]);
            const bf16x8 B0m = *(const bf16x8*)(&xs[lr0][lp - 1][g * 8]);
            const bf16x8 B0p = *(const bf16x8*)(&xs[lr0][lp + 1][g * 8]);
            const bf16x8 B10 = *(const bf16x8*)(&xs[lr1][lp][g * 8]);
            const bf16x8 B1m = *(const bf16x8*)(&xs[lr1][lp - 1][g * 8]);
            const bf16x8 B1p = *(const bf16x8*)(&xs[lr1][lp + 1][g * 8]);

            f32x4 a0 = {0.f, 0.f, 0.f, 0.f}, a1 = {0.f, 0.f, 0.f, 0.f};
            a0 = __builtin_amdgcn_mfma_f32_16x16x32_bf16(A[0][0], B00, a0, 0, 0, 0);
            a0 = __builtin_amdgcn_mfma_f32_16x16x32_bf16(A[0][1], B0m, a0, 0, 0, 0);
            a0 = __builtin_amdgcn_mfma_f32_16x16x32_bf16(A[0][2], B10, a0, 0, 0, 0);
            a0 = __builtin_amdgcn_mfma_f32_16x16x32_bf16(A[0][3], B1m, a0, 0, 0, 0);
            a1 = __builtin_amdgcn_mfma_f32_16x16x32_bf16(A[1][0], B0p, a1, 0, 0, 0);
            a1 = __builtin_amdgcn_mfma_f32_16x16x32_bf16(A[1][1], B00, a1, 0, 0, 0);
            a1 = __builtin_amdgcn_mfma_f32_16x16x32_bf16(A[1][2], B1p, a1, 0, 0, 0);
            a1 = __builtin_amdgcn_mfma_f32_16x16x32_bf16(A[1][3], B10, a1, 0, 0, 0);

            const int col = c0 + nt * 16 + n16;
            #pragma unroll
            for (int r = 0; r < 4; ++r) {
                const int oo = mt * 16 + 4 * g + r;
                const float v0 = a0[r] + bv4[r];
                const float v1 = a1[r] + bv4[r];
                float* p = out + ((size_t)(b * O_OUT + oo) * H_OUT + ho) * W_OUT + 2 * col;
                if (col == 0)             p[1] = v1;          // wo=0 is col-frame
                else if (col == W_IN - 1) p[0] = v0;          // wo=191 is col-frame
                else                      *(float2*)p = make_float2(v0, v1);
            }
        }
    } else {
        // ---- frame: border columns wo in {0,191} (ho 1..190) + 4 corners ----
        const int fb   = blk - NCBLK;        // 0..767
        const int z    = fb >> 3;            // (b,o)
        const int pseg = fb & 7;
        const int pl   = tid >> 3;           // 0..47
        const int cg   = tid & 7;
        const int p    = pseg * 48 + pl;     // 0..383, all valid
        const int b = z / O_OUT, o = z % O_OUT;

        int ho, wo;
        if      (p < 190) { ho = 1 + p;         wo = 0;   }
        else if (p < 380) { ho = 1 + (p - 190); wo = 191; }
        else { const int k = p - 380; ho = (k >> 1) ? 191 : 0; wo = (k & 1) ? 191 : 0; }

        const int s = ho >> 1, t = wo >> 1;

        int ii[2], ri[2], nr = 0;
        if (ho & 1) { ii[nr] = 2; ri[nr] = s; ++nr; if (s + 1 < H_IN) { ii[nr] = 0; ri[nr] = s + 1; ++nr; } }
        else        { ii[nr] = 1; ri[nr] = s; ++nr; if (s     >= 1  ) { ii[nr] = 3; ri[nr] = s - 1; ++nr; } }
        int jj[2], cj[2], nc = 0;
        if (wo & 1) { jj[nc] = 2; cj[nc] = t; ++nc; if (t + 1 < W_IN) { jj[nc] = 0; cj[nc] = t + 1; ++nc; } }
        else        { jj[nc] = 1; cj[nc] = t; ++nc; if (t     >= 1  ) { jj[nc] = 3; cj[nc] = t - 1; ++nc; } }

        const float* xb = x + (size_t)b * (C_IN * HW_IN);
        const float* wb = weight + (size_t)o * (C_IN * 16);

        float acc = 0.f;
        #pragma unroll
        for (int cc = 0; cc < 4; ++cc) {
            const int c = cg * 4 + cc;
            const float* xc  = xb + (size_t)c * HW_IN;
            const float* wcc = wb + c * 16;
            float y = 0.f, n = 0.f;
            for (int a = 0; a < nr; ++a)
                for (int d = 0; d < nc; ++d) {
                    const float wv = wcc[ii[a] * 4 + jj[d]];
                    y += wv * xc[ri[a] * W_IN + cj[d]];
                    n += wv;
                }
            acc += y / n;
        }

        acc += __shfl_xor(acc, 4);
        acc += __shfl_xor(acc, 2);
        acc += __shfl_xor(acc, 1);

        if (cg == 0)
            out[((size_t)z * H_OUT + ho) * W_OUT + wo] = acc + bias[o];
    }
}

extern "C" void kernel_launch(void* const* d_in, const int* in_sizes, int n_in,
                              void* d_out, int out_size, void* d_ws, size_t ws_size,
                              hipStream_t stream) {
    const float* x    = (const float*)d_in[0];
    const float* w    = (const float*)d_in[1];
    const float* bias = (const float*)d_in[2];
    float* out = (float*)d_out;

    dim3 b384(384, 1, 1);
    dim3 gm(NCBLK + NFBLK, 1, 1);                  // 1152 blocks, single launch
    hipLaunchKernelGGL(nct_all, gm, b384, 0, stream, x, w, bias, out);
}

// Round 11
// 26.414 us; speedup vs baseline: 1.1294x; 1.1294x over previous
//
#include <hip/hip_runtime.h>

#define C_IN  32
#define O_OUT 48
#define H_IN  96
#define W_IN  96
#define H_OUT 192
#define W_OUT 192
#define HW_IN (H_IN * W_IN)
#define NCBLK 384               // compute blocks: 2 b x 96 rows x 2 half
#define NFBLK 16                // frame blocks: 2 b x 2 side x 4 o-groups

typedef __attribute__((ext_vector_type(8))) short bf16x8;
typedef __attribute__((ext_vector_type(4))) float f32x4;

__device__ __forceinline__ unsigned short f2bf(float f) {
    union { float f; unsigned u; } v; v.f = f;
    unsigned u = v.u + 0x7FFFu + ((v.u >> 16) & 1u);
    return (unsigned short)(u >> 16);
}

// ---------------------------------------------------------------------------
// Single kernel, two block roles.
//
// Compute blocks [0,384): (b,row,half). Phase A transposes the 3x50x32 x-slab
// to LDS (bf16). Each of the 6 waves (pe,mt) builds its 8 MFMA A-fragments
// from RAW weights, folding the parity-class reciprocal norm and the row-edge
// class (ho=0/191: missing row-tap zeroed, norm over present row only).
// MFMA yields exact values for ALL rows; column borders wo in {0,191} are
// excluded by store predicates.
//
// Frame blocks [384,400): border columns wo in {0,191}, full ho range 0..191
// (corners included via row-edge masks). Needs only x[:, :, :, col*]:
// stage the 32x96 column in LDS once, then all reads are LDS broadcasts +
// broadcast weight loads -- kills the 9M-cache-line scatter of the old frame.
//
// Tap map (ts=a*2+d), pe=0 (even ho=2s): a0->i=1 (x row s), a1->i=3 (s-1)
//                     pe=1 (odd  ho)   : a0->i=0 (s+1),     a1->i=2 (s)
// po=0 (even wo=2t): d0->j=1 (col t), d1->j=3 (t-1)
// po=1 (odd  wo)   : d0->j=0 (t+1),  d1->j=2 (t)
// ---------------------------------------------------------------------------
__global__ __launch_bounds__(384) void nct_all(
    const float* __restrict__ x,       // [2,32,96,96]
    const float* __restrict__ weight,  // [48,32,4,4]
    const float* __restrict__ bias,    // [48]
    float* __restrict__ out)           // [2,48,192,192]
{
    __shared__ __align__(16) unsigned char smem[12288];
    const int blk = blockIdx.x;
    const int tid = threadIdx.x;

    if (blk < NCBLK) {
        auto xs = (unsigned short (*)[52][32])smem;   // [3][52][32] bf16

        int Wd = blk;
        const int half = Wd & 1; Wd >>= 1;
        const int row  = Wd % 96;
        const int b    = Wd / 96;
        const int c0   = half * 48;

        const int r3[3] = { (row > 0) ? row - 1 : 0, row, (row < H_IN - 1) ? row + 1 : H_IN - 1 };

        // ---- phase A: transpose 3 rows x 50 cols x 32 c into LDS ----
        for (int tau = tid; tau < 600; tau += 384) {
            const int r   = tau / 200;
            const int rem = tau - r * 200;
            const int pix = rem >> 2;
            const int cg  = rem & 3;
            int gcol = c0 - 1 + pix;
            gcol = (gcol < 0) ? 0 : ((gcol > W_IN - 1) ? W_IN - 1 : gcol);
            const float* src = x + (size_t)(b * C_IN + cg * 8) * HW_IN + r3[r] * W_IN + gcol;
            unsigned pk[4];
            #pragma unroll
            for (int k = 0; k < 4; ++k) {
                const float f0 = src[(size_t)(2 * k)     * HW_IN];
                const float f1 = src[(size_t)(2 * k + 1) * HW_IN];
                pk[k] = (unsigned)f2bf(f0) | ((unsigned)f2bf(f1) << 16);
            }
            *(uint4*)(&xs[r][pix][cg * 8]) = make_uint4(pk[0], pk[1], pk[2], pk[3]);
        }

        // ---- per-wave A-fragment build from raw weights ----
        const int lane = tid & 63;
        const int wid  = tid >> 6;     // 0..5
        const int pe = wid & 1, mt = wid >> 1;
        const int g = lane >> 4, n16 = lane & 15;

        const bool etop = (pe == 0 && row == 0);
        const bool ebot = (pe == 1 && row == H_IN - 1);
        const float m0 = ebot ? 0.f : 1.f;   // a0 tap present?
        const float m1 = etop ? 0.f : 1.f;   // a1 tap present?

        const int o = mt * 16 + n16;
        const float* wsrc = weight + ((size_t)o * C_IN + g * 8) * 16;

        bf16x8 A[2][4];
        #pragma unroll
        for (int cc = 0; cc < 8; ++cc) {
            const float4 w0 = *(const float4*)(wsrc + cc * 16);
            const float4 w1 = *(const float4*)(wsrc + cc * 16 + 4);
            const float4 w2 = *(const float4*)(wsrc + cc * 16 + 8);
            const float4 w3 = *(const float4*)(wsrc + cc * 16 + 12);
            const float4 wa0 = pe ? w0 : w1;   // a0 row taps
            const float4 wa1 = pe ? w2 : w3;   // a1 row taps

            const float r0 = 1.f / (m0 * (wa0.y + wa0.w) + m1 * (wa1.y + wa1.w)); // po=0
            const float r1 = 1.f / (m0 * (wa0.x + wa0.z) + m1 * (wa1.x + wa1.z)); // po=1

            A[0][0][cc] = (short)f2bf(m0 * wa0.y * r0);
            A[0][1][cc] = (short)f2bf(m0 * wa0.w * r0);
            A[0][2][cc] = (short)f2bf(m1 * wa1.y * r0);
            A[0][3][cc] = (short)f2bf(m1 * wa1.w * r0);
            A[1][0][cc] = (short)f2bf(m0 * wa0.x * r1);
            A[1][1][cc] = (short)f2bf(m0 * wa0.z * r1);
            A[1][2][cc] = (short)f2bf(m1 * wa1.x * r1);
            A[1][3][cc] = (short)f2bf(m1 * wa1.z * r1);
        }

        const float4 bv4 = *(const float4*)(bias + mt * 16 + 4 * g);

        __syncthreads();

        const int lr0 = pe ? 2 : 1;
        const int lr1 = pe ? 1 : 0;
        const int ho  = 2 * row + pe;

        #pragma unroll
        for (int nt = 0; nt < 3; ++nt) {
            const int lp = nt * 16 + n16 + 1;

            const bf16x8 B00 = *(const bf16x8*)(&xs[lr0][lp][g * 8]);
            const bf16x8 B0m = *(const bf16x8*)(&xs[lr0][lp - 1][g * 8]);
            const bf16x8 B0p = *(const bf16x8*)(&xs[lr0][lp + 1][g * 8]);
            const bf16x8 B10 = *(const bf16x8*)(&xs[lr1][lp][g * 8]);
            const bf16x8 B1m = *(const bf16x8*)(&xs[lr1][lp - 1][g * 8]);
            const bf16x8 B1p = *(const bf16x8*)(&xs[lr1][lp + 1][g * 8]);

            f32x4 a0 = {0.f, 0.f, 0.f, 0.f}, a1 = {0.f, 0.f, 0.f, 0.f};
            a0 = __builtin_amdgcn_mfma_f32_16x16x32_bf16(A[0][0], B00, a0, 0, 0, 0);
            a0 = __builtin_amdgcn_mfma_f32_16x16x32_bf16(A[0][1], B0m, a0, 0, 0, 0);
            a0 = __builtin_amdgcn_mfma_f32_16x16x32_bf16(A[0][2], B10, a0, 0, 0, 0);
            a0 = __builtin_amdgcn_mfma_f32_16x16x32_bf16(A[0][3], B1m, a0, 0, 0, 0);
            a1 = __builtin_amdgcn_mfma_f32_16x16x32_bf16(A[1][0], B0p, a1, 0, 0, 0);
            a1 = __builtin_amdgcn_mfma_f32_16x16x32_bf16(A[1][1], B00, a1, 0, 0, 0);
            a1 = __builtin_amdgcn_mfma_f32_16x16x32_bf16(A[1][2], B1p, a1, 0, 0, 0);
            a1 = __builtin_amdgcn_mfma_f32_16x16x32_bf16(A[1][3], B10, a1, 0, 0, 0);

            const int col = c0 + nt * 16 + n16;
            #pragma unroll
            for (int r = 0; r < 4; ++r) {
                const int oo = mt * 16 + 4 * g + r;
                const float v0 = a0[r] + bv4[r];
                const float v1 = a1[r] + bv4[r];
                float* p = out + ((size_t)(b * O_OUT + oo) * H_OUT + ho) * W_OUT + 2 * col;
                if (col == 0)             p[1] = v1;          // wo=0 is col-frame
                else if (col == W_IN - 1) p[0] = v0;          // wo=191 is col-frame
                else                      *(float2*)p = make_float2(v0, v1);
            }
        }
    } else {
        // ---- frame: border columns wo in {0,191}, ho 0..191 (corners incl.) ----
        float* xcol = (float*)smem;              // [32][96]

        const int fb   = blk - NCBLK;            // 0..15
        const int b    = fb >> 3;
        const int side = (fb >> 2) & 1;
        const int og   = fb & 3;

        const int o_loc  = tid >> 5;             // 0..11
        const int ho_loc = tid & 31;             // 0..31
        const int o      = og * 12 + o_loc;
        const int wo     = side ? 191 : 0;
        const int colx   = side ? 95 : 0;
        const int pe     = ho_loc & 1;
        const int jstar  = side ? 2 : 1;

        // stage x[:, :, :, colx] -> LDS [c][row]
        for (int idx = tid; idx < C_IN * H_IN; idx += 384) {
            const int c = idx / H_IN;
            const int r = idx - c * H_IN;
            xcol[c * H_IN + r] = x[(size_t)(b * C_IN + c) * HW_IN + r * W_IN + colx];
        }
        __syncthreads();

        // per-k row geometry (parity of ho is fixed per thread)
        int   rA[6], rB[6];
        float mBf[6];
        #pragma unroll
        for (int k = 0; k < 6; ++k) {
            const int ho = ho_loc + 32 * k;
            const int s  = ho >> 1;
            rA[k] = s;
            if (pe) { const bool m = (s + 1 < H_IN); rB[k] = m ? s + 1 : H_IN - 1; mBf[k] = m ? 1.f : 0.f; }
            else    { const bool m = (s > 0);        rB[k] = m ? s - 1 : 0;        mBf[k] = m ? 1.f : 0.f; }
        }

        const int iA = pe ? 8 : 4;    // w row-tap index base for rA (i=2 / i=1)
        const int iB = pe ? 0 : 12;   // for rB (i=0 / i=3)

        float acc[6] = {0.f, 0.f, 0.f, 0.f, 0.f, 0.f};
        const float* wb = weight + (size_t)o * (C_IN * 16);

        for (int c = 0; c < C_IN; ++c) {
            const float wA = wb[c * 16 + iA + jstar];
            const float wB = wb[c * 16 + iB + jstar];
            const float rn_int  = __builtin_amdgcn_rcpf(wA + wB);
            const float rn_edge = __builtin_amdgcn_rcpf(wA);
            const float* xc = xcol + c * H_IN;
            #pragma unroll
            for (int k = 0; k < 6; ++k) {
                const float xA = xc[rA[k]];
                const float xB = xc[rB[k]];
                const float rn = (mBf[k] != 0.f) ? rn_int : rn_edge;
                acc[k] += (wA * xA + mBf[k] * (wB * xB)) * rn;
            }
        }

        const float bv = bias[o];
        #pragma unroll
        for (int k = 0; k < 6; ++k) {
            const int ho = ho_loc + 32 * k;
            out[((size_t)(b * O_OUT + o) * H_OUT + ho) * W_OUT + wo] = acc[k] + bv;
        }
    }
}

extern "C" void kernel_launch(void* const* d_in, const int* in_sizes, int n_in,
                              void* d_out, int out_size, void* d_ws, size_t ws_size,
                              hipStream_t stream) {
    const float* x    = (const float*)d_in[0];
    const float* w    = (const float*)d_in[1];
    const float* bias = (const float*)d_in[2];
    float* out = (float*)d_out;

    dim3 b384(384, 1, 1);
    dim3 gm(NCBLK + NFBLK, 1, 1);                  // 400 blocks, single launch
    hipLaunchKernelGGL(nct_all, gm, b384, 0, stream, x, w, bias, out);
}